// Round 4
// baseline (228.601 us; speedup 1.0000x reference)
//
#include <hip/hip_runtime.h>
#include <hip/hip_bf16.h>
#include <math.h>

#define NN 512
#define CSD 384
#define CZ 128
#define HH 12
#define TMPW 1152          // 192 sq | 192 sk | 192 sv | 144 pq | 144 pk | 288 pv
#define CATH 176
#define CATDIM 2112
#define NSPLIT 6
#define KSPL 352

#define SW 0.14433756729740643f
#define PW 0.13608276348795434f
#define ZW 0.57735026918962576f
#define NEG_INF -3.4028234663852886e38f

typedef float f32x4_t __attribute__((ext_vector_type(4)));
typedef short bf16x8_t __attribute__((ext_vector_type(8)));

union BFU { uint4 q; bf16x8_t v; ushort u[8]; };

static __device__ __forceinline__ ushort f2bf(float f) {
    __hip_bfloat16 h = __float2bfloat16(f);
    return *reinterpret_cast<ushort*>(&h);
}
static __device__ __forceinline__ float bf2f(ushort u) {
    unsigned int v = ((unsigned int)u) << 16;
    return __uint_as_float(v);
}

// ---------------- proj GEMM: tmp[512][1152] = s[512][384] @ Wcat + bias
__global__ void proj_gemm_kernel(const float* __restrict__ s,
                                 const float* __restrict__ Wsq, const float* __restrict__ bsq,
                                 const float* __restrict__ Wsk, const float* __restrict__ bsk,
                                 const float* __restrict__ Wsv, const float* __restrict__ bsv,
                                 const float* __restrict__ Wpq, const float* __restrict__ bpq,
                                 const float* __restrict__ Wpk, const float* __restrict__ bpk,
                                 const float* __restrict__ Wpv, const float* __restrict__ bpv,
                                 float* __restrict__ tmp)
{
    int bx = blockIdx.x;            // 24 f-tiles of 48
    int n0 = blockIdx.y * 32;       // 16 n-tiles
    int f0 = bx * 48;
    const float* W; const float* bb; int dout; int segstart;
    if (bx < 4)       { W = Wsq; bb = bsq; dout = 192; segstart = 0; }
    else if (bx < 8)  { W = Wsk; bb = bsk; dout = 192; segstart = 192; }
    else if (bx < 12) { W = Wsv; bb = bsv; dout = 192; segstart = 384; }
    else if (bx < 15) { W = Wpq; bb = bpq; dout = 144; segstart = 576; }
    else if (bx < 18) { W = Wpk; bb = bpk; dout = 144; segstart = 720; }
    else              { W = Wpv; bb = bpv; dout = 288; segstart = 864; }
    int colbase = f0 - segstart;

    __shared__ float St[32][34];
    __shared__ float Ws[32][49];
    int tid = threadIdx.x;
    int ty = tid >> 4, tx = tid & 15;
    float acc[2][3] = {{0,0,0},{0,0,0}};

    for (int k0 = 0; k0 < CSD; k0 += 32) {
        {
            int r = tid >> 3, c4 = (tid & 7) * 4;
            float4 v = *(const float4*)&s[(size_t)(n0 + r) * CSD + k0 + c4];
            St[c4 + 0][r] = v.x; St[c4 + 1][r] = v.y; St[c4 + 2][r] = v.z; St[c4 + 3][r] = v.w;
        }
        for (int e = tid; e < 1536; e += 256) {
            int r = e / 48, c = e % 48;
            Ws[r][c] = W[(size_t)(k0 + r) * dout + colbase + c];
        }
        __syncthreads();
        #pragma unroll
        for (int k = 0; k < 32; k++) {
            float2 a = *(const float2*)&St[k][ty * 2];
            float b0 = Ws[k][tx * 3], b1 = Ws[k][tx * 3 + 1], b2 = Ws[k][tx * 3 + 2];
            acc[0][0] += a.x * b0; acc[0][1] += a.x * b1; acc[0][2] += a.x * b2;
            acc[1][0] += a.y * b0; acc[1][1] += a.y * b1; acc[1][2] += a.y * b2;
        }
        __syncthreads();
    }
    float bv0 = bb[colbase + tx * 3], bv1 = bb[colbase + tx * 3 + 1], bv2 = bb[colbase + tx * 3 + 2];
    #pragma unroll
    for (int r = 0; r < 2; r++) {
        float* o = tmp + (size_t)(n0 + ty * 2 + r) * TMPW + f0 + tx * 3;
        o[0] = acc[r][0] + bv0; o[1] = acc[r][1] + bv1; o[2] = acc[r][2] + bv2;
    }
}

// ---------------- rotate point projections to global frame, in place on tmp
__global__ void rotate_kernel(const float* __restrict__ rot, const float* __restrict__ tran,
                              float* __restrict__ tmp)
{
    int pid = blockIdx.x * 256 + threadIdx.x;   // 512*192 points
    int n = pid / 192, q = pid % 192;
    float* p = tmp + (size_t)n * TMPW + 576 + q * 3;
    float v0 = p[0], v1 = p[1], v2 = p[2];
    const float* R = rot + n * 9;
    const float* T = tran + n * 3;
    p[0] = R[0] * v0 + R[1] * v1 + R[2] * v2 + T[0];
    p[1] = R[3] * v0 + R[4] * v1 + R[5] * v2 + T[1];
    p[2] = R[6] * v0 + R[7] * v1 + R[8] * v2 + T[2];
}

// ---------------- fused logits + softmax: block per i, z streamed from global.
// attn written as bf16 (ushort).
__global__ void logits_softmax_kernel(const float* __restrict__ z, const float* __restrict__ resm,
                                      const float* __restrict__ Wsb, const float* __restrict__ bsb,
                                      const float* __restrict__ watt, const float* __restrict__ batt,
                                      const float* __restrict__ tpw, const float* __restrict__ tmp,
                                      ushort* __restrict__ attn_bf)
{
    int i = blockIdx.x;
    __shared__ float wt[HH * 132];      // scaled Wsb^T [h][c], pad 132
    __shared__ float lt[NN * 17];       // logits [j][h], pad 17 (34.8 KB)
    __shared__ float sqs[192];
    __shared__ float pqi[144];
    __shared__ float cpt[12];
    __shared__ float cb[12];
    int tid = threadIdx.x;
    float w0 = watt[0], w1 = watt[1], w2 = watt[2], ba = batt[0];
    float A2 = w2 * ZW;

    for (int k = tid; k < 1536; k += 256) {
        int c = k / 12, h = k % 12;
        wt[h * 132 + c] = Wsb[k] * A2;
    }
    for (int k = tid; k < 192; k += 256) sqs[k] = tmp[(size_t)i * TMPW + k] * (SW * w0);
    if (tid < 144) pqi[tid] = tmp[(size_t)i * TMPW + 576 + tid];
    if (tid < 12) {
        cpt[tid] = -0.5f * log1pf(expf(tpw[tid])) * PW * w1;
        cb[tid]  = A2 * bsb[tid] + ba;
    }
    __syncthreads();

    int jg = tid >> 2, hg = tid & 3, h0 = hg * 3;
    float rmi = resm[i];
    const float* wa = &wt[(h0 + 0) * 132];
    const float* wb = &wt[(h0 + 1) * 132];
    const float* wc = &wt[(h0 + 2) * 132];

    #pragma unroll
    for (int b = 0; b < 2; b++) {
        int jb = b * 256 + jg;              // rows jb + 64*rr, rr=0..3
        float acc[4][3];
        #pragma unroll
        for (int rr = 0; rr < 4; rr++) { acc[rr][0] = 0.f; acc[rr][1] = 0.f; acc[rr][2] = 0.f; }
        const float* zr = z + ((size_t)i * NN + jb) * CZ;

        for (int c = 0; c < CZ; c += 4) {
            float4 u0 = *(const float4*)&wa[c];
            float4 u1 = *(const float4*)&wb[c];
            float4 u2 = *(const float4*)&wc[c];
            #pragma unroll
            for (int rr = 0; rr < 4; rr++) {
                float4 zv = *(const float4*)&zr[(size_t)rr * 64 * CZ + c];
                acc[rr][0] += zv.x * u0.x + zv.y * u0.y + zv.z * u0.z + zv.w * u0.w;
                acc[rr][1] += zv.x * u1.x + zv.y * u1.y + zv.z * u1.z + zv.w * u1.w;
                acc[rr][2] += zv.x * u2.x + zv.y * u2.y + zv.z * u2.z + zv.w * u2.w;
            }
        }

        #pragma unroll
        for (int rr = 0; rr < 4; rr++) {
            int j = jb + rr * 64;
            float mj = rmi * resm[j];
            #pragma unroll
            for (int t = 0; t < 3; t++) {
                int h = h0 + t;
                const float4* skp = (const float4*)(tmp + (size_t)j * TMPW + 192 + h * 16);
                const float4* sqp = (const float4*)&sqs[h * 16];
                float d0 = 0.f;
                #pragma unroll
                for (int q = 0; q < 4; q++) {
                    float4 kv = skp[q];
                    float4 qv = sqp[q];
                    d0 += qv.x * kv.x + qv.y * kv.y + qv.z * kv.z + qv.w * kv.w;
                }
                const float4* pkp = (const float4*)(tmp + (size_t)j * TMPW + 720 + h * 12);
                const float4* pqp = (const float4*)&pqi[h * 12];
                float sd = 0.f;
                #pragma unroll
                for (int q = 0; q < 3; q++) {
                    float4 kv = pkp[q];
                    float4 qv = pqp[q];
                    float a = qv.x - kv.x, bb2 = qv.y - kv.y, cc = qv.z - kv.z, e = qv.w - kv.w;
                    sd += a * a + bb2 * bb2 + cc * cc + e * e;
                }
                float lg = cb[h] + acc[rr][t] + d0 + cpt[h] * sd;
                if (mj == 0.f) lg = NEG_INF;
                lt[j * 17 + h] = lg;
            }
        }
    }
    __syncthreads();

    // softmax over j per head; write bf16 attn
    int wid = tid >> 6, lane = tid & 63;
    #pragma unroll
    for (int t = 0; t < 3; t++) {
        int h = wid * 3 + t;
        float v[8]; float m = -INFINITY;
        #pragma unroll
        for (int u = 0; u < 8; u++) { v[u] = lt[(lane + 64 * u) * 17 + h]; m = fmaxf(m, v[u]); }
        for (int off = 32; off; off >>= 1) m = fmaxf(m, __shfl_xor(m, off));
        float ssum = 0.f;
        #pragma unroll
        for (int u = 0; u < 8; u++) { v[u] = __expf(v[u] - m); ssum += v[u]; }
        for (int off = 32; off; off >>= 1) ssum += __shfl_xor(ssum, off);
        float inv = 1.f / ssum;
        ushort* ag = attn_bf + ((size_t)i * HH + h) * NN;
        #pragma unroll
        for (int u = 0; u < 8; u++) ag[lane + 64 * u] = f2bf(v[u] * inv);
    }
}

// ---------------- r_pair via MFMA: cat[i][h*176+48+c] = sum_j attn[i][h][j] * z[i][j][c]
// block per i; A = P bf16 [16][512] in LDS (granule-XOR swizzled), B = z from global (cvt bf16)
__global__ void rpair_mfma_kernel(const float* __restrict__ z, const ushort* __restrict__ attn_bf,
                                  float* __restrict__ cat)
{
    int i = blockIdx.x;
    __shared__ uint4 Pl[16 * 64];       // 16 rows x 64 granules of 8 bf16 (16 KB)
    int tid = threadIdx.x;

    const ushort* ab = attn_bf + (size_t)i * HH * NN;
    #pragma unroll
    for (int u = 0; u < 4; u++) {
        int s2 = tid + 256 * u;         // 1024 granule tasks
        int m = s2 >> 6, g = s2 & 63;
        uint4 val;
        if (m < HH) val = *(const uint4*)&ab[(size_t)m * NN + g * 8];
        else { val.x = 0; val.y = 0; val.z = 0; val.w = 0; }
        Pl[m * 64 + (g ^ (m & 7))] = val;
    }
    __syncthreads();

    int w = tid >> 6, lane = tid & 63;
    int l16 = lane & 15, lhi = lane >> 4;
    int c0a = (w * 2 + 0) * 16, c0b = (w * 2 + 1) * 16;
    f32x4_t acc0 = {0.f, 0.f, 0.f, 0.f};
    f32x4_t acc1 = {0.f, 0.f, 0.f, 0.f};

    for (int kk = 0; kk < 16; kk++) {
        // A fragment: P[m = l16][k = kk*32 + lhi*8 + e]
        int gidx = kk * 4 + lhi;
        BFU au;
        au.q = Pl[l16 * 64 + (gidx ^ (l16 & 7))];
        // B fragments: z[k][n] with k = kk*32 + lhi*8 + e, n = c0 + l16
        const float* zb = z + ((size_t)i * NN + kk * 32 + lhi * 8) * CZ;
        BFU b0, b1;
        #pragma unroll
        for (int e = 0; e < 8; e++) {
            b0.u[e] = f2bf(zb[(size_t)e * CZ + c0a + l16]);
            b1.u[e] = f2bf(zb[(size_t)e * CZ + c0b + l16]);
        }
        acc0 = __builtin_amdgcn_mfma_f32_16x16x32_bf16(au.v, b0.v, acc0, 0, 0, 0);
        acc1 = __builtin_amdgcn_mfma_f32_16x16x32_bf16(au.v, b1.v, acc1, 0, 0, 0);
    }

    // D: col = lane&15 (= c offset), row = (lane>>4)*4 + reg (= h)
    #pragma unroll
    for (int r = 0; r < 4; r++) {
        int h = lhi * 4 + r;
        if (h < HH) {
            float* cp = cat + (size_t)i * CATDIM + h * CATH + 48;
            cp[c0a + l16] = acc0[r];
            cp[c0b + l16] = acc1[r];
        }
    }
}

// ---------------- per-head r_scalar + r_pt (+rotate back, norm); attn now bf16
__global__ void head_sum_kernel(const ushort* __restrict__ attn_bf, const float* __restrict__ tmp,
                                const float* __restrict__ rot, const float* __restrict__ tran,
                                float* __restrict__ cat)
{
    int i0 = blockIdx.x * 32;
    int h  = blockIdx.y;
    __shared__ float At[32][65];
    __shared__ float Sr[64][44];
    __shared__ float Rp[32][24];
    int tid = threadIdx.x;
    int il = tid & 31, fg = tid >> 5;
    float acc[5] = {0,0,0,0,0};

    for (int jc = 0; jc < NN; jc += 64) {
        {
            int r = tid >> 3, c8 = (tid & 7) * 8;
            const ushort* src = attn_bf + ((size_t)(i0 + r) * HH + h) * NN + jc + c8;
            BFU v; v.q = *(const uint4*)src;
            #pragma unroll
            for (int q = 0; q < 8; q++) At[r][c8 + q] = bf2f(v.u[q]);
        }
        {
            int jr = tid >> 2, d4 = (tid & 3) * 4;
            *(float4*)&Sr[jr][d4] = *(const float4*)&tmp[(size_t)(jc + jr) * TMPW + 384 + h * 16 + d4];
        }
        for (int e = tid; e < 384; e += 256) {
            int jr = e / 6, p4 = (e % 6) * 4;
            *(float4*)&Sr[jr][16 + p4] = *(const float4*)&tmp[(size_t)(jc + jr) * TMPW + 864 + h * 24 + p4];
        }
        __syncthreads();
        #pragma unroll 4
        for (int j = 0; j < 64; j++) {
            float a = At[il][j];
            #pragma unroll
            for (int q = 0; q < 5; q++) acc[q] += a * Sr[j][fg * 5 + q];
        }
        __syncthreads();
    }

    float* cbase = cat + (size_t)(i0 + il) * CATDIM + h * CATH;
    #pragma unroll
    for (int q = 0; q < 5; q++) {
        int f = fg * 5 + q;
        if (f < 16) cbase[f] = acc[q];
        else Rp[il][f - 16] = acc[q];
    }
    __syncthreads();

    {
        int il2 = tid >> 3, p = tid & 7;
        int i = i0 + il2;
        float gx = Rp[il2][p * 3 + 0] - tran[i * 3 + 0];
        float gy = Rp[il2][p * 3 + 1] - tran[i * 3 + 1];
        float gz = Rp[il2][p * 3 + 2] - tran[i * 3 + 2];
        const float* R = rot + i * 9;
        float lx = R[0] * gx + R[3] * gy + R[6] * gz;
        float ly = R[1] * gx + R[4] * gy + R[7] * gz;
        float lz = R[2] * gx + R[5] * gy + R[8] * gz;
        float nrm = sqrtf(lx * lx + ly * ly + lz * lz + 1e-8f);
        float* cp = cat + (size_t)i * CATDIM + h * CATH;
        cp[16 + p * 3 + 0] = lx; cp[16 + p * 3 + 1] = ly; cp[16 + p * 3 + 2] = lz;
        cp[40 + p] = nrm;
    }
}

// ---------------- out GEMM, K-split
__global__ void out_gemm_split_kernel(const float* __restrict__ cat, const float* __restrict__ Wout,
                                      float* __restrict__ part)
{
    int n0 = blockIdx.x * 64;
    int i0 = blockIdx.y * 64;
    int ks = blockIdx.z * KSPL;
    __shared__ float St[32][68];
    __shared__ float Bs[32][68];
    int tid = threadIdx.x;
    int ty = tid >> 4, tx = tid & 15;
    float acc[4][4] = {{0,0,0,0},{0,0,0,0},{0,0,0,0},{0,0,0,0}};

    for (int k0 = 0; k0 < KSPL; k0 += 32) {
        {
            int r = tid >> 2, c8 = (tid & 3) * 8;
            const float* src = cat + (size_t)(i0 + r) * CATDIM + ks + k0 + c8;
            float4 v0 = *(const float4*)src;
            float4 v1 = *(const float4*)(src + 4);
            St[c8+0][r]=v0.x; St[c8+1][r]=v0.y; St[c8+2][r]=v0.z; St[c8+3][r]=v0.w;
            St[c8+4][r]=v1.x; St[c8+5][r]=v1.y; St[c8+6][r]=v1.z; St[c8+7][r]=v1.w;
        }
        {
            int r = tid >> 3, c8 = (tid & 7) * 8;
            const float* src = Wout + (size_t)(ks + k0 + r) * CSD + n0 + c8;
            *(float4*)&Bs[r][c8]     = *(const float4*)src;
            *(float4*)&Bs[r][c8 + 4] = *(const float4*)(src + 4);
        }
        __syncthreads();
        #pragma unroll
        for (int k = 0; k < 32; k++) {
            float4 a = *(const float4*)&St[k][ty * 4];
            float4 b = *(const float4*)&Bs[k][tx * 4];
            float av[4] = {a.x, a.y, a.z, a.w};
            float bv[4] = {b.x, b.y, b.z, b.w};
            #pragma unroll
            for (int r = 0; r < 4; r++)
                #pragma unroll
                for (int c = 0; c < 4; c++) acc[r][c] += av[r] * bv[c];
        }
        __syncthreads();
    }
    #pragma unroll
    for (int r = 0; r < 4; r++) {
        float4 v = make_float4(acc[r][0], acc[r][1], acc[r][2], acc[r][3]);
        *(float4*)&part[((size_t)blockIdx.z * NN + i0 + ty * 4 + r) * CSD + n0 + tx * 4] = v;
    }
}

__global__ void reduce_out_kernel(const float* __restrict__ part, const float* __restrict__ bout,
                                  float* __restrict__ out)
{
    int v = blockIdx.x * 256 + threadIdx.x;
    int n4 = v % 96;
    float4 o = ((const float4*)bout)[n4];
    const float4* p4 = (const float4*)part;
    #pragma unroll
    for (int s = 0; s < NSPLIT; s++) {
        float4 t = p4[(size_t)s * 49152 + v];
        o.x += t.x; o.y += t.y; o.z += t.z; o.w += t.w;
    }
    ((float4*)out)[v] = o;
}

extern "C" void kernel_launch(void* const* d_in, const int* in_sizes, int n_in,
                              void* d_out, int out_size, void* d_ws, size_t ws_size,
                              hipStream_t stream) {
    const float* s    = (const float*)d_in[0];
    const float* z    = (const float*)d_in[1];
    const float* rot  = (const float*)d_in[2];
    const float* tran = (const float*)d_in[3];
    const float* resm = (const float*)d_in[4];
    const float* Wsq  = (const float*)d_in[5];  const float* bsq = (const float*)d_in[6];
    const float* Wsk  = (const float*)d_in[7];  const float* bsk = (const float*)d_in[8];
    const float* Wsv  = (const float*)d_in[9];  const float* bsv = (const float*)d_in[10];
    const float* Wsb  = (const float*)d_in[11]; const float* bsb = (const float*)d_in[12];
    const float* Wpq  = (const float*)d_in[13]; const float* bpq = (const float*)d_in[14];
    const float* Wpk  = (const float*)d_in[15]; const float* bpk = (const float*)d_in[16];
    const float* Wpv  = (const float*)d_in[17]; const float* bpv = (const float*)d_in[18];
    const float* watt = (const float*)d_in[19]; const float* batt = (const float*)d_in[20];
    const float* tpw  = (const float*)d_in[21];
    const float* Wout = (const float*)d_in[22]; const float* bout = (const float*)d_in[23];
    float* out = (float*)d_out;
    float* ws  = (float*)d_ws;

    float* tmp      = ws;                       // 512*1152 = 589824 floats
    ushort* attn_bf = (ushort*)(ws + 589824);   // 512*12*512 ushorts = 1572864 floats
    float* cat      = ws + 589824 + 1572864;    // 512*2112 = 1081344
    float* partO    = cat + 1081344;            // 6*512*384 = 1179648

    proj_gemm_kernel<<<dim3(24, 16), 256, 0, stream>>>(s, Wsq, bsq, Wsk, bsk, Wsv, bsv,
                                                       Wpq, bpq, Wpk, bpk, Wpv, bpv, tmp);
    rotate_kernel<<<384, 256, 0, stream>>>(rot, tran, tmp);
    logits_softmax_kernel<<<512, 256, 0, stream>>>(z, resm, Wsb, bsb, watt, batt, tpw,
                                                   tmp, attn_bf);
    rpair_mfma_kernel<<<512, 256, 0, stream>>>(z, attn_bf, cat);
    head_sum_kernel<<<dim3(16, 12), 256, 0, stream>>>(attn_bf, tmp, rot, tran, cat);
    out_gemm_split_kernel<<<dim3(6, 8, NSPLIT), 256, 0, stream>>>(cat, Wout, partO);
    reduce_out_kernel<<<192, 256, 0, stream>>>(partO, bout, out);
}

// Round 5
// 190.020 us; speedup vs baseline: 1.2030x; 1.2030x over previous
//
#include <hip/hip_runtime.h>
#include <hip/hip_bf16.h>
#include <math.h>

#define NN 512
#define CSD 384
#define CZ 128
#define HH 12
#define TMPW 1152          // 192 sq | 192 sk | 192 sv | 144 pq | 144 pk | 288 pv
#define CATH 176
#define CATDIM 2112
#define NSPLIT 6
#define KSPL 352

#define SW 0.14433756729740643f
#define PW 0.13608276348795434f
#define ZW 0.57735026918962576f
#define NEG_INF -3.4028234663852886e38f

typedef float f32x4_t __attribute__((ext_vector_type(4)));
typedef short bf16x8_t __attribute__((ext_vector_type(8)));

union BFU { uint4 q; bf16x8_t v; ushort u[8]; };

static __device__ __forceinline__ ushort f2bf(float f) {
    __hip_bfloat16 h = __float2bfloat16(f);
    return *reinterpret_cast<ushort*>(&h);
}
static __device__ __forceinline__ float bf2f(ushort u) {
    unsigned int v = ((unsigned int)u) << 16;
    return __uint_as_float(v);
}

// ---------------- proj GEMM: tmp[512][1152] = s[512][384] @ Wcat + bias
__global__ void proj_gemm_kernel(const float* __restrict__ s,
                                 const float* __restrict__ Wsq, const float* __restrict__ bsq,
                                 const float* __restrict__ Wsk, const float* __restrict__ bsk,
                                 const float* __restrict__ Wsv, const float* __restrict__ bsv,
                                 const float* __restrict__ Wpq, const float* __restrict__ bpq,
                                 const float* __restrict__ Wpk, const float* __restrict__ bpk,
                                 const float* __restrict__ Wpv, const float* __restrict__ bpv,
                                 float* __restrict__ tmp)
{
    int bx = blockIdx.x;            // 24 f-tiles of 48
    int n0 = blockIdx.y * 32;       // 16 n-tiles
    int f0 = bx * 48;
    const float* W; const float* bb; int dout; int segstart;
    if (bx < 4)       { W = Wsq; bb = bsq; dout = 192; segstart = 0; }
    else if (bx < 8)  { W = Wsk; bb = bsk; dout = 192; segstart = 192; }
    else if (bx < 12) { W = Wsv; bb = bsv; dout = 192; segstart = 384; }
    else if (bx < 15) { W = Wpq; bb = bpq; dout = 144; segstart = 576; }
    else if (bx < 18) { W = Wpk; bb = bpk; dout = 144; segstart = 720; }
    else              { W = Wpv; bb = bpv; dout = 288; segstart = 864; }
    int colbase = f0 - segstart;

    __shared__ float St[32][34];
    __shared__ float Ws[32][49];
    int tid = threadIdx.x;
    int ty = tid >> 4, tx = tid & 15;
    float acc[2][3] = {{0,0,0},{0,0,0}};

    for (int k0 = 0; k0 < CSD; k0 += 32) {
        {
            int r = tid >> 3, c4 = (tid & 7) * 4;
            float4 v = *(const float4*)&s[(size_t)(n0 + r) * CSD + k0 + c4];
            St[c4 + 0][r] = v.x; St[c4 + 1][r] = v.y; St[c4 + 2][r] = v.z; St[c4 + 3][r] = v.w;
        }
        for (int e = tid; e < 1536; e += 256) {
            int r = e / 48, c = e % 48;
            Ws[r][c] = W[(size_t)(k0 + r) * dout + colbase + c];
        }
        __syncthreads();
        #pragma unroll
        for (int k = 0; k < 32; k++) {
            float2 a = *(const float2*)&St[k][ty * 2];
            float b0 = Ws[k][tx * 3], b1 = Ws[k][tx * 3 + 1], b2 = Ws[k][tx * 3 + 2];
            acc[0][0] += a.x * b0; acc[0][1] += a.x * b1; acc[0][2] += a.x * b2;
            acc[1][0] += a.y * b0; acc[1][1] += a.y * b1; acc[1][2] += a.y * b2;
        }
        __syncthreads();
    }
    float bv0 = bb[colbase + tx * 3], bv1 = bb[colbase + tx * 3 + 1], bv2 = bb[colbase + tx * 3 + 2];
    #pragma unroll
    for (int r = 0; r < 2; r++) {
        float* o = tmp + (size_t)(n0 + ty * 2 + r) * TMPW + f0 + tx * 3;
        o[0] = acc[r][0] + bv0; o[1] = acc[r][1] + bv1; o[2] = acc[r][2] + bv2;
    }
}

// ---------------- rotate point projections to global frame, in place on tmp
__global__ void rotate_kernel(const float* __restrict__ rot, const float* __restrict__ tran,
                              float* __restrict__ tmp)
{
    int pid = blockIdx.x * 256 + threadIdx.x;   // 512*192 points
    int n = pid / 192, q = pid % 192;
    float* p = tmp + (size_t)n * TMPW + 576 + q * 3;
    float v0 = p[0], v1 = p[1], v2 = p[2];
    const float* R = rot + n * 9;
    const float* T = tran + n * 3;
    p[0] = R[0] * v0 + R[1] * v1 + R[2] * v2 + T[0];
    p[1] = R[3] * v0 + R[4] * v1 + R[5] * v2 + T[1];
    p[2] = R[6] * v0 + R[7] * v1 + R[8] * v2 + T[2];
}

// ---------------- pair-bias GEMM via MFMA: sbz[r][h] = (z_flat[r][:] @ Wsb[:,h]) * w2*ZW
// r = i*512+j flat over 262144 rows. B-fragments (Wsb) held in registers for whole kernel.
// grid 1024 blocks x 256 thr; block = 256 rows; wave = 4 x 16-row tiles. No LDS, no barriers.
__global__ void pairbias_mfma_kernel(const float* __restrict__ z, const float* __restrict__ Wsb,
                                     const float* __restrict__ watt, float* __restrict__ sbz)
{
    int tid = threadIdx.x;
    int w = tid >> 6, lane = tid & 63;
    int l16 = lane & 15, lhi = lane >> 4;
    float A2 = watt[2] * ZW;

    BFU breg[4];
    #pragma unroll
    for (int kk = 0; kk < 4; kk++) {
        #pragma unroll
        for (int e = 0; e < 8; e++) {
            int k = kk * 32 + lhi * 8 + e;
            float v = (l16 < HH) ? Wsb[k * HH + l16] * A2 : 0.f;
            breg[kk].u[e] = f2bf(v);
        }
    }

    #pragma unroll
    for (int t = 0; t < 4; t++) {
        size_t r0 = (size_t)blockIdx.x * 256 + (size_t)(t * 4 + w) * 16;
        const float* zrow = z + (r0 + l16) * CZ;
        f32x4_t acc = {0.f, 0.f, 0.f, 0.f};
        #pragma unroll
        for (int kk = 0; kk < 4; kk++) {
            int k0 = kk * 32 + lhi * 8;
            float4 f0 = *(const float4*)&zrow[k0];
            float4 f1 = *(const float4*)&zrow[k0 + 4];
            BFU a;
            a.u[0] = f2bf(f0.x); a.u[1] = f2bf(f0.y); a.u[2] = f2bf(f0.z); a.u[3] = f2bf(f0.w);
            a.u[4] = f2bf(f1.x); a.u[5] = f2bf(f1.y); a.u[6] = f2bf(f1.z); a.u[7] = f2bf(f1.w);
            acc = __builtin_amdgcn_mfma_f32_16x16x32_bf16(a.v, breg[kk].v, acc, 0, 0, 0);
        }
        if (l16 < HH) {
            #pragma unroll
            for (int r = 0; r < 4; r++)
                sbz[(r0 + lhi * 4 + r) * HH + l16] = acc[r];
        }
    }
}

// ---------------- fused logits + softmax (no z!): block per i.
// pair term read from sbz; scalar+point terms from L2-hot tmp. attn written bf16.
__global__ void logits_softmax_kernel(const float* __restrict__ sbz, const float* __restrict__ resm,
                                      const float* __restrict__ bsb,
                                      const float* __restrict__ watt, const float* __restrict__ batt,
                                      const float* __restrict__ tpw, const float* __restrict__ tmp,
                                      ushort* __restrict__ attn_bf)
{
    int i = blockIdx.x;
    __shared__ float lt[NN * 17];       // logits [j][h], pad 17 (34.8 KB)
    __shared__ float sqs[192];
    __shared__ float pqi[144];
    __shared__ float cpt[12];
    __shared__ float cb[12];
    int tid = threadIdx.x;
    float w0 = watt[0], w1 = watt[1], w2 = watt[2], ba = batt[0];
    float A2 = w2 * ZW;

    for (int k = tid; k < 192; k += 256) sqs[k] = tmp[(size_t)i * TMPW + k] * (SW * w0);
    if (tid < 144) pqi[tid] = tmp[(size_t)i * TMPW + 576 + tid];
    if (tid < 12) {
        cpt[tid] = -0.5f * log1pf(expf(tpw[tid])) * PW * w1;
        cb[tid]  = A2 * bsb[tid] + ba;
    }
    __syncthreads();

    int jg = tid >> 2, hg = tid & 3, h0 = hg * 3;
    float rmi = resm[i];
    const float* sbi = sbz + (size_t)i * NN * HH;

    #pragma unroll
    for (int rr = 0; rr < 8; rr++) {
        int j = jg + 64 * rr;
        float mj = rmi * resm[j];
        const float* sbr = &sbi[(size_t)j * HH + h0];
        float pb[3] = { sbr[0], sbr[1], sbr[2] };
        #pragma unroll
        for (int t = 0; t < 3; t++) {
            int h = h0 + t;
            const float4* skp = (const float4*)(tmp + (size_t)j * TMPW + 192 + h * 16);
            const float4* sqp = (const float4*)&sqs[h * 16];
            float d0 = 0.f;
            #pragma unroll
            for (int q = 0; q < 4; q++) {
                float4 kv = skp[q];
                float4 qv = sqp[q];
                d0 += qv.x * kv.x + qv.y * kv.y + qv.z * kv.z + qv.w * kv.w;
            }
            const float4* pkp = (const float4*)(tmp + (size_t)j * TMPW + 720 + h * 12);
            const float4* pqp = (const float4*)&pqi[h * 12];
            float sd = 0.f;
            #pragma unroll
            for (int q = 0; q < 3; q++) {
                float4 kv = pkp[q];
                float4 qv = pqp[q];
                float a = qv.x - kv.x, bb2 = qv.y - kv.y, cc = qv.z - kv.z, e = qv.w - kv.w;
                sd += a * a + bb2 * bb2 + cc * cc + e * e;
            }
            float lg = cb[h] + pb[t] + d0 + cpt[h] * sd;
            if (mj == 0.f) lg = NEG_INF;
            lt[j * 17 + h] = lg;
        }
    }
    __syncthreads();

    // softmax over j per head; write bf16 attn
    int wid = tid >> 6, lane = tid & 63;
    #pragma unroll
    for (int t = 0; t < 3; t++) {
        int h = wid * 3 + t;
        float v[8]; float m = -INFINITY;
        #pragma unroll
        for (int u = 0; u < 8; u++) { v[u] = lt[(lane + 64 * u) * 17 + h]; m = fmaxf(m, v[u]); }
        for (int off = 32; off; off >>= 1) m = fmaxf(m, __shfl_xor(m, off));
        float ssum = 0.f;
        #pragma unroll
        for (int u = 0; u < 8; u++) { v[u] = __expf(v[u] - m); ssum += v[u]; }
        for (int off = 32; off; off >>= 1) ssum += __shfl_xor(ssum, off);
        float inv = 1.f / ssum;
        ushort* ag = attn_bf + ((size_t)i * HH + h) * NN;
        #pragma unroll
        for (int u = 0; u < 8; u++) ag[lane + 64 * u] = f2bf(v[u] * inv);
    }
}

// ---------------- r_pair via MFMA: cat[i][h*176+48+c] = sum_j attn[i][h][j] * z[i][j][c]
__global__ void rpair_mfma_kernel(const float* __restrict__ z, const ushort* __restrict__ attn_bf,
                                  float* __restrict__ cat)
{
    int i = blockIdx.x;
    __shared__ uint4 Pl[16 * 64];       // 16 rows x 64 granules of 8 bf16 (16 KB)
    int tid = threadIdx.x;

    const ushort* ab = attn_bf + (size_t)i * HH * NN;
    #pragma unroll
    for (int u = 0; u < 4; u++) {
        int s2 = tid + 256 * u;         // 1024 granule tasks
        int m = s2 >> 6, g = s2 & 63;
        uint4 val;
        if (m < HH) val = *(const uint4*)&ab[(size_t)m * NN + g * 8];
        else { val.x = 0; val.y = 0; val.z = 0; val.w = 0; }
        Pl[m * 64 + (g ^ (m & 7))] = val;
    }
    __syncthreads();

    int w = tid >> 6, lane = tid & 63;
    int l16 = lane & 15, lhi = lane >> 4;
    int c0a = (w * 2 + 0) * 16, c0b = (w * 2 + 1) * 16;
    f32x4_t acc0 = {0.f, 0.f, 0.f, 0.f};
    f32x4_t acc1 = {0.f, 0.f, 0.f, 0.f};

    for (int kk = 0; kk < 16; kk++) {
        int gidx = kk * 4 + lhi;
        BFU au;
        au.q = Pl[l16 * 64 + (gidx ^ (l16 & 7))];
        const float* zb = z + ((size_t)i * NN + kk * 32 + lhi * 8) * CZ;
        BFU b0, b1;
        #pragma unroll
        for (int e = 0; e < 8; e++) {
            b0.u[e] = f2bf(zb[(size_t)e * CZ + c0a + l16]);
            b1.u[e] = f2bf(zb[(size_t)e * CZ + c0b + l16]);
        }
        acc0 = __builtin_amdgcn_mfma_f32_16x16x32_bf16(au.v, b0.v, acc0, 0, 0, 0);
        acc1 = __builtin_amdgcn_mfma_f32_16x16x32_bf16(au.v, b1.v, acc1, 0, 0, 0);
    }

    #pragma unroll
    for (int r = 0; r < 4; r++) {
        int h = lhi * 4 + r;
        if (h < HH) {
            float* cp = cat + (size_t)i * CATDIM + h * CATH + 48;
            cp[c0a + l16] = acc0[r];
            cp[c0b + l16] = acc1[r];
        }
    }
}

// ---------------- per-head r_scalar + r_pt (+rotate back, norm); attn bf16
__global__ void head_sum_kernel(const ushort* __restrict__ attn_bf, const float* __restrict__ tmp,
                                const float* __restrict__ rot, const float* __restrict__ tran,
                                float* __restrict__ cat)
{
    int i0 = blockIdx.x * 32;
    int h  = blockIdx.y;
    __shared__ float At[32][65];
    __shared__ float Sr[64][44];
    __shared__ float Rp[32][24];
    int tid = threadIdx.x;
    int il = tid & 31, fg = tid >> 5;
    float acc[5] = {0,0,0,0,0};

    for (int jc = 0; jc < NN; jc += 64) {
        {
            int r = tid >> 3, c8 = (tid & 7) * 8;
            const ushort* src = attn_bf + ((size_t)(i0 + r) * HH + h) * NN + jc + c8;
            BFU v; v.q = *(const uint4*)src;
            #pragma unroll
            for (int q = 0; q < 8; q++) At[r][c8 + q] = bf2f(v.u[q]);
        }
        {
            int jr = tid >> 2, d4 = (tid & 3) * 4;
            *(float4*)&Sr[jr][d4] = *(const float4*)&tmp[(size_t)(jc + jr) * TMPW + 384 + h * 16 + d4];
        }
        for (int e = tid; e < 384; e += 256) {
            int jr = e / 6, p4 = (e % 6) * 4;
            *(float4*)&Sr[jr][16 + p4] = *(const float4*)&tmp[(size_t)(jc + jr) * TMPW + 864 + h * 24 + p4];
        }
        __syncthreads();
        #pragma unroll 4
        for (int j = 0; j < 64; j++) {
            float a = At[il][j];
            #pragma unroll
            for (int q = 0; q < 5; q++) acc[q] += a * Sr[j][fg * 5 + q];
        }
        __syncthreads();
    }

    float* cbase = cat + (size_t)(i0 + il) * CATDIM + h * CATH;
    #pragma unroll
    for (int q = 0; q < 5; q++) {
        int f = fg * 5 + q;
        if (f < 16) cbase[f] = acc[q];
        else Rp[il][f - 16] = acc[q];
    }
    __syncthreads();

    {
        int il2 = tid >> 3, p = tid & 7;
        int i = i0 + il2;
        float gx = Rp[il2][p * 3 + 0] - tran[i * 3 + 0];
        float gy = Rp[il2][p * 3 + 1] - tran[i * 3 + 1];
        float gz = Rp[il2][p * 3 + 2] - tran[i * 3 + 2];
        const float* R = rot + i * 9;
        float lx = R[0] * gx + R[3] * gy + R[6] * gz;
        float ly = R[1] * gx + R[4] * gy + R[7] * gz;
        float lz = R[2] * gx + R[5] * gy + R[8] * gz;
        float nrm = sqrtf(lx * lx + ly * ly + lz * lz + 1e-8f);
        float* cp = cat + (size_t)i * CATDIM + h * CATH;
        cp[16 + p * 3 + 0] = lx; cp[16 + p * 3 + 1] = ly; cp[16 + p * 3 + 2] = lz;
        cp[40 + p] = nrm;
    }
}

// ---------------- out GEMM, K-split
__global__ void out_gemm_split_kernel(const float* __restrict__ cat, const float* __restrict__ Wout,
                                      float* __restrict__ part)
{
    int n0 = blockIdx.x * 64;
    int i0 = blockIdx.y * 64;
    int ks = blockIdx.z * KSPL;
    __shared__ float St[32][68];
    __shared__ float Bs[32][68];
    int tid = threadIdx.x;
    int ty = tid >> 4, tx = tid & 15;
    float acc[4][4] = {{0,0,0,0},{0,0,0,0},{0,0,0,0},{0,0,0,0}};

    for (int k0 = 0; k0 < KSPL; k0 += 32) {
        {
            int r = tid >> 2, c8 = (tid & 3) * 8;
            const float* src = cat + (size_t)(i0 + r) * CATDIM + ks + k0 + c8;
            float4 v0 = *(const float4*)src;
            float4 v1 = *(const float4*)(src + 4);
            St[c8+0][r]=v0.x; St[c8+1][r]=v0.y; St[c8+2][r]=v0.z; St[c8+3][r]=v0.w;
            St[c8+4][r]=v1.x; St[c8+5][r]=v1.y; St[c8+6][r]=v1.z; St[c8+7][r]=v1.w;
        }
        {
            int r = tid >> 3, c8 = (tid & 7) * 8;
            const float* src = Wout + (size_t)(ks + k0 + r) * CSD + n0 + c8;
            *(float4*)&Bs[r][c8]     = *(const float4*)src;
            *(float4*)&Bs[r][c8 + 4] = *(const float4*)(src + 4);
        }
        __syncthreads();
        #pragma unroll
        for (int k = 0; k < 32; k++) {
            float4 a = *(const float4*)&St[k][ty * 4];
            float4 b = *(const float4*)&Bs[k][tx * 4];
            float av[4] = {a.x, a.y, a.z, a.w};
            float bv[4] = {b.x, b.y, b.z, b.w};
            #pragma unroll
            for (int r = 0; r < 4; r++)
                #pragma unroll
                for (int c = 0; c < 4; c++) acc[r][c] += av[r] * bv[c];
        }
        __syncthreads();
    }
    #pragma unroll
    for (int r = 0; r < 4; r++) {
        float4 v = make_float4(acc[r][0], acc[r][1], acc[r][2], acc[r][3]);
        *(float4*)&part[((size_t)blockIdx.z * NN + i0 + ty * 4 + r) * CSD + n0 + tx * 4] = v;
    }
}

__global__ void reduce_out_kernel(const float* __restrict__ part, const float* __restrict__ bout,
                                  float* __restrict__ out)
{
    int v = blockIdx.x * 256 + threadIdx.x;
    int n4 = v % 96;
    float4 o = ((const float4*)bout)[n4];
    const float4* p4 = (const float4*)part;
    #pragma unroll
    for (int s = 0; s < NSPLIT; s++) {
        float4 t = p4[(size_t)s * 49152 + v];
        o.x += t.x; o.y += t.y; o.z += t.z; o.w += t.w;
    }
    ((float4*)out)[v] = o;
}

extern "C" void kernel_launch(void* const* d_in, const int* in_sizes, int n_in,
                              void* d_out, int out_size, void* d_ws, size_t ws_size,
                              hipStream_t stream) {
    const float* s    = (const float*)d_in[0];
    const float* z    = (const float*)d_in[1];
    const float* rot  = (const float*)d_in[2];
    const float* tran = (const float*)d_in[3];
    const float* resm = (const float*)d_in[4];
    const float* Wsq  = (const float*)d_in[5];  const float* bsq = (const float*)d_in[6];
    const float* Wsk  = (const float*)d_in[7];  const float* bsk = (const float*)d_in[8];
    const float* Wsv  = (const float*)d_in[9];  const float* bsv = (const float*)d_in[10];
    const float* Wsb  = (const float*)d_in[11]; const float* bsb = (const float*)d_in[12];
    const float* Wpq  = (const float*)d_in[13]; const float* bpq = (const float*)d_in[14];
    const float* Wpk  = (const float*)d_in[15]; const float* bpk = (const float*)d_in[16];
    const float* Wpv  = (const float*)d_in[17]; const float* bpv = (const float*)d_in[18];
    const float* watt = (const float*)d_in[19]; const float* batt = (const float*)d_in[20];
    const float* tpw  = (const float*)d_in[21];
    const float* Wout = (const float*)d_in[22]; const float* bout = (const float*)d_in[23];
    float* out = (float*)d_out;
    float* ws  = (float*)d_ws;

    float* tmp      = ws;                        // 512*1152 = 589824 floats
    ushort* attn_bf = (ushort*)(ws + 589824);    // 3145728 ushorts = 1572864 float-slots
    float* sbz      = ws + 589824 + 1572864;     // 262144*12 = 3145728 floats
    float* cat      = sbz + 3145728;             // 512*2112 = 1081344
    float* partO    = cat + 1081344;             // 6*512*384 = 1179648

    proj_gemm_kernel<<<dim3(24, 16), 256, 0, stream>>>(s, Wsq, bsq, Wsk, bsk, Wsv, bsv,
                                                       Wpq, bpq, Wpk, bpk, Wpv, bpv, tmp);
    rotate_kernel<<<384, 256, 0, stream>>>(rot, tran, tmp);
    pairbias_mfma_kernel<<<1024, 256, 0, stream>>>(z, Wsb, watt, sbz);
    logits_softmax_kernel<<<512, 256, 0, stream>>>(sbz, resm, bsb, watt, batt, tpw,
                                                   tmp, attn_bf);
    rpair_mfma_kernel<<<512, 256, 0, stream>>>(z, attn_bf, cat);
    head_sum_kernel<<<dim3(16, 12), 256, 0, stream>>>(attn_bf, tmp, rot, tran, cat);
    out_gemm_split_kernel<<<dim3(6, 8, NSPLIT), 256, 0, stream>>>(cat, Wout, partO);
    reduce_out_kernel<<<192, 256, 0, stream>>>(partO, bout, out);
}